// Round 7
// baseline (866.009 us; speedup 1.0000x reference)
//
#include <hip/hip_runtime.h>
#include <cstddef>

#define HH 256
#define WW 256
#define NB 4
#define NFC 64
#define EMBC 512

typedef short s16x8 __attribute__((ext_vector_type(8)));
typedef float f32x4 __attribute__((ext_vector_type(4)));

#define GLOBAL_AS __attribute__((address_space(1)))
#define LDS_AS __attribute__((address_space(3)))

static __device__ __forceinline__ unsigned short f2b(float f) {
    unsigned int u = __float_as_uint(f);
    u += 0x7FFFu + ((u >> 16) & 1u);
    return (unsigned short)(u >> 16);
}

// ---------------------------------------------------------------------------
// Modulated weights -> bf16 [b][tap][co][ci]. Block (co,b), 64 thr (ci).
// ---------------------------------------------------------------------------
__global__ void modw_kernel(const float* __restrict__ emb, const float* __restrict__ mw,
                            const float* __restrict__ mb, const float* __restrict__ bw,
                            unsigned short* __restrict__ outw)
{
    const int co = blockIdx.x, b = blockIdx.y;
    const int ci = threadIdx.x;

    const float* e = emb + (size_t)b * EMBC;
    const float* m = mw + (size_t)ci * EMBC;
    float s = mb[ci];
    for (int k = 0; k < EMBC; k += 4) {
        float4 ev = *(const float4*)(e + k);
        float4 mv = *(const float4*)(m + k);
        s += ev.x * mv.x + ev.y * mv.y + ev.z * mv.z + ev.w * mv.w;
    }

    float w[9];
    float ss = 0.f;
    const float* src = bw + ((size_t)co * NFC + ci) * 9;
#pragma unroll
    for (int k = 0; k < 9; ++k) {
        float v = (1.0f / 24.0f) * src[k] * s;
        w[k] = v;
        ss += v * v;
    }
#pragma unroll
    for (int off = 32; off; off >>= 1) ss += __shfl_xor(ss, off);
    float demod = rsqrtf(ss + 1e-8f);

#pragma unroll
    for (int k = 0; k < 9; ++k)
        outw[(((size_t)b * 9 + k) * NFC + co) * NFC + ci] = f2b(w[k] * demod);
}

// ---------------------------------------------------------------------------
// Fixed-weight transform: w[co][ci][3][3] f32 -> wt[tap][COP][64] bf16
// ---------------------------------------------------------------------------
__global__ void fixw_kernel(const float* __restrict__ w, unsigned short* __restrict__ wt,
                            int Cout, int COP)
{
    int idx = blockIdx.x * 256 + threadIdx.x;
    int total = 9 * COP * NFC;
    if (idx >= total) return;
    int k = idx / (COP * NFC);
    int rem = idx - k * (COP * NFC);
    int co = rem / NFC, ci = rem - co * NFC;
    float v = (co < Cout) ? w[((size_t)co * NFC + ci) * 9 + k] : 0.f;
    wt[idx] = f2b(v);
}

// ---------------------------------------------------------------------------
// conv_first weights: [64][3][3][3] f32 -> [64][32] bf16 (k = ci*9+kh*3+kw, pad)
// ---------------------------------------------------------------------------
__global__ void firstw_kernel(const float* __restrict__ w, unsigned short* __restrict__ wt)
{
    int idx = blockIdx.x * 256 + threadIdx.x;   // 64*32
    if (idx >= 64 * 32) return;
    int co = idx >> 5, k = idx & 31;
    wt[idx] = (k < 27) ? f2b(w[co * 27 + k]) : 0;
}

// ---------------------------------------------------------------------------
// im2col for layer 0: fp32 NCHW x -> bf16 [px][32], k = ci*9+kh*3+kw (27 real)
// ---------------------------------------------------------------------------
__global__ __launch_bounds__(256) void im2col_kernel(
    const float* __restrict__ x, unsigned short* __restrict__ ib)
{
    const int p = blockIdx.x * 256 + threadIdx.x;          // 0 .. 4*256*256-1
    const int b = p >> 16, hw = p & 0xFFFF;
    const int h = hw >> 8, w = hw & 255;

    unsigned short kv[32];
#pragma unroll
    for (int ci = 0; ci < 3; ++ci)
#pragma unroll
        for (int kh = 0; kh < 3; ++kh)
#pragma unroll
            for (int kw = 0; kw < 3; ++kw) {
                int gh = h + kh - 1, gw = w + kw - 1;
                float v = 0.f;
                if ((unsigned)gh < HH && (unsigned)gw < WW)
                    v = x[(((size_t)b * 3 + ci) * HH + gh) * WW + gw];
                kv[ci * 9 + kh * 3 + kw] = f2b(v);
            }
#pragma unroll
    for (int k = 27; k < 32; ++k) kv[k] = 0;

    unsigned short* op = ib + (size_t)p * 32;
#pragma unroll
    for (int q = 0; q < 4; ++q)
        *(uint4*)(op + q * 8) = *(const uint4*)(kv + q * 8);
}

// ---------------------------------------------------------------------------
// Layer 0 GEMM: [px][32] x [64][32] -> bf16 NHWC, bias+lrelu. K=32 single step.
// ---------------------------------------------------------------------------
__global__ __launch_bounds__(256) void conv_first_mm(
    const unsigned short* __restrict__ ib, const unsigned short* __restrict__ wt,
    const float* __restrict__ bias, unsigned short* __restrict__ out)
{
    __shared__ unsigned short tb[4][16][72];   // per-wave transpose buffer
    const int lane = threadIdx.x & 63, wid = threadIdx.x >> 6;
    const int m16 = lane & 15, kg = lane >> 4;

    s16x8 a[4];
    float4 bv[4];
#pragma unroll
    for (int mf = 0; mf < 4; ++mf) {
        a[mf] = *(const s16x8*)(wt + (mf * 16 + m16) * 32 + kg * 8);
        bv[mf] = *(const float4*)(bias + mf * 16 + kg * 4);
    }

    const int t0 = blockIdx.x * 16 + wid * 4;
#pragma unroll
    for (int t = 0; t < 4; ++t) {
        const size_t px0 = (size_t)(t0 + t) * 16;
        s16x8 bfr = *(const s16x8*)(ib + (px0 + m16) * 32 + kg * 8);
#pragma unroll
        for (int mf = 0; mf < 4; ++mf) {
            f32x4 c = (f32x4)(0.f);
            c = __builtin_amdgcn_mfma_f32_16x16x32_bf16(a[mf], bfr, c, 0, 0, 0);
            unsigned short pk[4];
#pragma unroll
            for (int e = 0; e < 4; ++e) {
                float v = c[e] + (&bv[mf].x)[e];
                v = v >= 0.f ? v : 0.1f * v;
                pk[e] = f2b(v);
            }
            *(uint2*)&tb[wid][m16][mf * 16 + kg * 4] = *(uint2*)pk;
        }
        asm volatile("s_waitcnt lgkmcnt(0)" ::: "memory");
#pragma unroll
        for (int s = 0; s < 2; ++s) {
            const int p = s * 8 + (lane >> 3);
            uint4 rd = *(const uint4*)&tb[wid][p][(lane & 7) * 8];
            *(uint4*)(out + (px0 + p) * NFC + (lane & 7) * 8) = rd;
        }
    }
}

// ---------------------------------------------------------------------------
// Main MFMA conv. Interior tiles: staging via global_load_lds DMA (no VGPRs,
// 54 x 1KB DMAs in flight, pre-swizzled global source, linear LDS dest).
// Border tiles: register staging path (handles zero-padding).
// ---------------------------------------------------------------------------
template <int MFRAGS, bool PERB, bool BIAS, bool LRELU, bool NOISE, bool OUTF32>
__global__ __launch_bounds__(256, 3) void mconv(
    const unsigned short* __restrict__ in, const unsigned short* __restrict__ wt,
    const float* __restrict__ bias, const float* __restrict__ noise,
    const float* __restrict__ wnp, void* __restrict__ outv)
{
    constexpr int COP = MFRAGS * 16;
    __shared__ uint4 xs[18 * 18 * 8];            // 41472 B
    __shared__ unsigned short tb[4][16][72];     // 9216 B, per-wave C transpose

    const int tid = threadIdx.x;
    // XCD-aware swizzle: 1024 blocks, 8 XCDs -> contiguous 128-block chunks
    const int flat = blockIdx.x;
    const int swz = (flat & 7) * 128 + (flat >> 3);
    const int b = swz >> 8, remb = swz & 255;
    const int th = remb >> 4, tw = remb & 15;
    const int h0 = th * 16, w0 = tw * 16;

    const int lane = tid & 63, wid = tid >> 6;
    const int m16 = lane & 15, kg = lane >> 4;

    const unsigned short* wbase = PERB ? wt + (size_t)b * 9 * COP * NFC : wt;
    const unsigned short* wlane = wbase + m16 * NFC + kg * 8;

    auto LOADA = [&](int g, s16x8* a) {
        const unsigned short* p = wlane + (size_t)(g >> 1) * (COP * NFC) + (g & 1) * 32;
#pragma unroll
        for (int mf = 0; mf < MFRAGS; ++mf)
            a[mf] = *(const s16x8*)(p + mf * 16 * NFC);
    };

    s16x8 abuf[4][MFRAGS];
    LOADA(0, abuf[0]); LOADA(1, abuf[1]); LOADA(2, abuf[2]);

    const bool interior = (th > 0) && (th < 15) && (tw > 0) && (tw < 15);
    if (interior) {
        // 54 DMAs: i = row*3 + part; part -> j0 in {-1, 7, 9} (8 px each,
        // part 2 overlaps part 1 by 6 px: same data, same LDS addr, benign).
        for (int i = wid; i < 54; i += 4) {
            const int row = i / 3, part = i - row * 3;         // wave-uniform
            const int j0 = (part == 0) ? -1 : (part == 1) ? 7 : 9;
            const int gh = h0 + row - 1;
            const int j = j0 + (lane >> 3);                    // per-lane px
            const int gw = w0 + j;
            const int w = j + 1;                               // LDS w index
            // lane writes LDS slot sigma=lane&7 of pixel w; fetch global slot sigma^(w&7)
            const unsigned short* gp = in + (((size_t)b * HH + gh) * WW + gw) * NFC
                                          + ((lane & 7) ^ (w & 7)) * 8;
            uint4* lp = &xs[(size_t)(row * 18 + (j0 + 1)) * 8];
            __builtin_amdgcn_global_load_lds(
                (const GLOBAL_AS void*)gp, (LDS_AS void*)lp, 16, 0, 0);
        }
    } else {
        // register path with zero-padding (border tiles)
        uint4 u[11];
#pragma unroll
        for (int i = 0; i < 11; ++i) {
            const int idx = tid + i * 256;
            u[i] = make_uint4(0, 0, 0, 0);
            if (idx < 2592) {
                const int row = idx / 144, rem2 = idx - row * 144;
                const int w = rem2 >> 3, slot = rem2 & 7;
                const int gh = h0 + row - 1, gw = w0 + w - 1;
                if ((unsigned)gh < HH && (unsigned)gw < WW)
                    u[i] = *(const uint4*)(in + (((size_t)b * HH + gh) * WW + gw) * NFC + slot * 8);
            }
        }
#pragma unroll
        for (int i = 0; i < 11; ++i) {
            const int idx = tid + i * 256;
            if (idx < 2592) {
                const int row = idx / 144, rem2 = idx - row * 144;
                const int w = rem2 >> 3, slot = rem2 & 7;
                xs[(row * 18 + w) * 8 + (slot ^ (w & 7))] = u[i];
            }
        }
    }
    __syncthreads();

    f32x4 acc[MFRAGS][4];
#pragma unroll
    for (int mf = 0; mf < MFRAGS; ++mf)
#pragma unroll
        for (int r = 0; r < 4; ++r) acc[mf][r] = (f32x4)(0.f);

#pragma unroll
    for (int g = 0; g < 18; ++g) {
        const int tap = g >> 1, half = g & 1;
        const int kh = tap / 3, kw = tap - kh * 3;
        const int lw = m16 + kw;
        const int slot = (half * 4 + kg) ^ (lw & 7);

        if (g + 3 < 18) LOADA(g + 3, abuf[(g + 3) & 3]);

        s16x8 bf[4];
#pragma unroll
        for (int r = 0; r < 4; ++r) {
            const int lrow = wid * 4 + r + kh;
            bf[r] = *(const s16x8*)&xs[(lrow * 18 + lw) * 8 + slot];
        }
#pragma unroll
        for (int r = 0; r < 4; ++r)
#pragma unroll
            for (int mf = 0; mf < MFRAGS; ++mf)
                acc[mf][r] = __builtin_amdgcn_mfma_f32_16x16x32_bf16(
                    abuf[g & 3][mf], bf[r], acc[mf][r], 0, 0, 0);
    }

    // --- epilogue ---
    const float wn = NOISE ? wnp[0] : 0.f;
#pragma unroll
    for (int r = 0; r < 4; ++r) {
        const int h = h0 + wid * 4 + r;
        float nz = 0.f;
        if (NOISE) nz = noise[((size_t)b * HH + h) * WW + w0 + m16];

        if (!OUTF32) {
#pragma unroll
            for (int mf = 0; mf < MFRAGS; ++mf) {
                const int cob = mf * 16 + kg * 4;
                f32x4 v = acc[mf][r];
                float4 bvv = make_float4(0.f, 0.f, 0.f, 0.f);
                if (BIAS) bvv = *(const float4*)(bias + cob);
                unsigned short pk[4];
#pragma unroll
                for (int e = 0; e < 4; ++e) {
                    float t = v[e] + (BIAS ? (&bvv.x)[e] : 0.f);
                    if (NOISE) t += wn * nz;
                    if (LRELU) t = t >= 0.f ? t : 0.1f * t;
                    pk[e] = f2b(t);
                }
                *(uint2*)&tb[wid][m16][cob] = *(uint2*)pk;
            }
            asm volatile("s_waitcnt lgkmcnt(0)" ::: "memory");
            unsigned short* ob = (unsigned short*)outv;
#pragma unroll
            for (int s = 0; s < 2; ++s) {
                const int p = s * 8 + (lane >> 3);
                uint4 rd = *(const uint4*)&tb[wid][p][(lane & 7) * 8];
                *(uint4*)(ob + (((size_t)b * HH + h) * WW + w0 + p) * NFC + (lane & 7) * 8) = rd;
            }
        } else {
#pragma unroll
            for (int mf = 0; mf < MFRAGS; ++mf) {
                const int cob = mf * 16 + kg * 4;
                f32x4 v = acc[mf][r];
                float4 bvv = make_float4(0.f, 0.f, 0.f, 0.f);
                if (BIAS) bvv = *(const float4*)(bias + cob);
                float* of = (float*)outv;
#pragma unroll
                for (int e = 0; e < 4; ++e) {
                    float t = v[e] + (BIAS ? (&bvv.x)[e] : 0.f);
                    if (NOISE) t += wn * nz;
                    if (LRELU) t = t >= 0.f ? t : 0.1f * t;
                    int co = cob + e;
                    if (co < 3)
                        of[(((size_t)b * 3 + co) * HH + h) * WW + w0 + m16] = t;
                }
            }
        }
    }
}

// ---------------------------------------------------------------------------
extern "C" void kernel_launch(void* const* d_in, const int* in_sizes, int n_in,
                              void* d_out, int out_size, void* d_ws, size_t ws_size,
                              hipStream_t stream)
{
    auto F = [&](int i) { return (const float*)d_in[i]; };
    const float* x       = F(0);
    const float* emb     = F(1);
    const float* noise[3] = {F(2), F(3), F(4)};
    const float* w_first = F(5);  const float* b_first = F(6);
    const float* w_hr[5] = {F(7), F(9), F(11), F(13), F(15)};
    const float* b_hr[5] = {F(8), F(10), F(12), F(14), F(16)};
    const float* w_last  = F(17); const float* b_last = F(18);
    const float *m_mw[3], *m_mb[3], *m_w[3], *m_cw[3], *m_cb[3], *m_wn[3];
    for (int i = 0; i < 3; ++i) {
        int o = 19 + 6 * i;
        m_mw[i] = F(o); m_mb[i] = F(o + 1); m_w[i] = F(o + 2);
        m_cw[i] = F(o + 3); m_cb[i] = F(o + 4); m_wn[i] = F(o + 5);
    }

    // workspace layout (bf16 = unsigned short)
    const size_t ACT = (size_t)NB * HH * WW * NFC;
    const size_t NPX = (size_t)NB * HH * WW;
    unsigned short* act0 = (unsigned short*)d_ws;
    unsigned short* act1 = act0 + ACT;
    unsigned short* p = act1 + ACT;
    unsigned short* wmod[3];
    for (int i = 0; i < 3; ++i) { wmod[i] = p; p += (size_t)NB * 9 * NFC * NFC; }
    unsigned short* wfix[8];
    for (int i = 0; i < 8; ++i) { wfix[i] = p; p += (size_t)9 * NFC * NFC; }
    unsigned short* wlast = p;  p += 9 * 16 * NFC;
    unsigned short* wfirst = p; p += 64 * 32;
    unsigned short* ib = p;     // [NPX][32]

    // --- weight prep + im2col ---
    dim3 mg(NFC, NB);
    for (int i = 0; i < 3; ++i)
        modw_kernel<<<mg, NFC, 0, stream>>>(emb, m_mw[i], m_mb[i], m_w[i], wmod[i]);
    for (int i = 0; i < 3; ++i)
        fixw_kernel<<<(9 * 64 * 64 + 255) / 256, 256, 0, stream>>>(m_cw[i], wfix[i], 64, 64);
    for (int i = 0; i < 5; ++i)
        fixw_kernel<<<(9 * 64 * 64 + 255) / 256, 256, 0, stream>>>(w_hr[i], wfix[3 + i], 64, 64);
    fixw_kernel<<<(9 * 16 * 64 + 255) / 256, 256, 0, stream>>>(w_last, wlast, 3, 16);
    firstw_kernel<<<8, 256, 0, stream>>>(w_first, wfirst);
    im2col_kernel<<<NPX / 256, 256, 0, stream>>>(x, ib);

    // layer 0
    conv_first_mm<<<1024, 256, 0, stream>>>(ib, wfirst, b_first, act0);

    const int grid = 1024;   // flattened; mconv swizzles internally
    unsigned short* cur = act0;
    unsigned short* nxt = act1;
    auto swap = [&]() { unsigned short* t = cur; cur = nxt; nxt = t; };

    for (int i = 0; i < 3; ++i) {
        mconv<4, true, false, false, true, false>
            <<<grid, 256, 0, stream>>>(cur, wmod[i], nullptr, noise[i], m_wn[i], nxt);
        swap();
        mconv<4, false, true, true, false, false>
            <<<grid, 256, 0, stream>>>(cur, wfix[i], m_cb[i], nullptr, nullptr, nxt);
        swap();
        mconv<4, false, true, false, false, false>
            <<<grid, 256, 0, stream>>>(cur, wfix[3 + i], b_hr[i], nullptr, nullptr, nxt);
        swap();
    }
    mconv<4, false, true, false, false, false>
        <<<grid, 256, 0, stream>>>(cur, wfix[6], b_hr[3], nullptr, nullptr, nxt);
    swap();
    mconv<4, false, true, false, false, false>
        <<<grid, 256, 0, stream>>>(cur, wfix[7], b_hr[4], nullptr, nullptr, nxt);
    swap();
    mconv<1, false, true, false, false, true>
        <<<grid, 256, 0, stream>>>(cur, wlast, b_last, nullptr, nullptr, d_out);
}

// Round 8
// 833.683 us; speedup vs baseline: 1.0388x; 1.0388x over previous
//
#include <hip/hip_runtime.h>
#include <cstddef>

#define HH 256
#define WW 256
#define NB 4
#define NFC 64
#define EMBC 512

typedef short s16x8 __attribute__((ext_vector_type(8)));
typedef float f32x4 __attribute__((ext_vector_type(4)));

#define GLOBAL_AS __attribute__((address_space(1)))
#define LDS_AS __attribute__((address_space(3)))

static __device__ __forceinline__ unsigned short f2b(float f) {
    unsigned int u = __float_as_uint(f);
    u += 0x7FFFu + ((u >> 16) & 1u);
    return (unsigned short)(u >> 16);
}

// ---------------------------------------------------------------------------
// Modulated weights -> bf16 [b][tap][co][ci]. Block (co,b), 64 thr (ci).
// ---------------------------------------------------------------------------
__global__ void modw_kernel(const float* __restrict__ emb, const float* __restrict__ mw,
                            const float* __restrict__ mb, const float* __restrict__ bw,
                            unsigned short* __restrict__ outw)
{
    const int co = blockIdx.x, b = blockIdx.y;
    const int ci = threadIdx.x;

    const float* e = emb + (size_t)b * EMBC;
    const float* m = mw + (size_t)ci * EMBC;
    float s = mb[ci];
    for (int k = 0; k < EMBC; k += 4) {
        float4 ev = *(const float4*)(e + k);
        float4 mv = *(const float4*)(m + k);
        s += ev.x * mv.x + ev.y * mv.y + ev.z * mv.z + ev.w * mv.w;
    }

    float w[9];
    float ss = 0.f;
    const float* src = bw + ((size_t)co * NFC + ci) * 9;
#pragma unroll
    for (int k = 0; k < 9; ++k) {
        float v = (1.0f / 24.0f) * src[k] * s;
        w[k] = v;
        ss += v * v;
    }
#pragma unroll
    for (int off = 32; off; off >>= 1) ss += __shfl_xor(ss, off);
    float demod = rsqrtf(ss + 1e-8f);

#pragma unroll
    for (int k = 0; k < 9; ++k)
        outw[(((size_t)b * 9 + k) * NFC + co) * NFC + ci] = f2b(w[k] * demod);
}

// ---------------------------------------------------------------------------
// Fixed-weight transform: w[co][ci][3][3] f32 -> wt[tap][COP][64] bf16
// ---------------------------------------------------------------------------
__global__ void fixw_kernel(const float* __restrict__ w, unsigned short* __restrict__ wt,
                            int Cout, int COP)
{
    int idx = blockIdx.x * 256 + threadIdx.x;
    int total = 9 * COP * NFC;
    if (idx >= total) return;
    int k = idx / (COP * NFC);
    int rem = idx - k * (COP * NFC);
    int co = rem / NFC, ci = rem - co * NFC;
    float v = (co < Cout) ? w[((size_t)co * NFC + ci) * 9 + k] : 0.f;
    wt[idx] = f2b(v);
}

// ---------------------------------------------------------------------------
// conv_first weights: [64][3][3][3] f32 -> [64][32] bf16 (k = ci*9+kh*3+kw, pad)
// ---------------------------------------------------------------------------
__global__ void firstw_kernel(const float* __restrict__ w, unsigned short* __restrict__ wt)
{
    int idx = blockIdx.x * 256 + threadIdx.x;   // 64*32
    if (idx >= 64 * 32) return;
    int co = idx >> 5, k = idx & 31;
    wt[idx] = (k < 27) ? f2b(w[co * 27 + k]) : 0;
}

// ---------------------------------------------------------------------------
// im2col for layer 0: fp32 NCHW x -> bf16 [px][32], k = ci*9+kh*3+kw (27 real)
// ---------------------------------------------------------------------------
__global__ __launch_bounds__(256) void im2col_kernel(
    const float* __restrict__ x, unsigned short* __restrict__ ib)
{
    const int p = blockIdx.x * 256 + threadIdx.x;          // 0 .. 4*256*256-1
    const int b = p >> 16, hw = p & 0xFFFF;
    const int h = hw >> 8, w = hw & 255;

    unsigned short kv[32];
#pragma unroll
    for (int ci = 0; ci < 3; ++ci)
#pragma unroll
        for (int kh = 0; kh < 3; ++kh)
#pragma unroll
            for (int kw = 0; kw < 3; ++kw) {
                int gh = h + kh - 1, gw = w + kw - 1;
                float v = 0.f;
                if ((unsigned)gh < HH && (unsigned)gw < WW)
                    v = x[(((size_t)b * 3 + ci) * HH + gh) * WW + gw];
                kv[ci * 9 + kh * 3 + kw] = f2b(v);
            }
#pragma unroll
    for (int k = 27; k < 32; ++k) kv[k] = 0;

    unsigned short* op = ib + (size_t)p * 32;
#pragma unroll
    for (int q = 0; q < 4; ++q)
        *(uint4*)(op + q * 8) = *(const uint4*)(kv + q * 8);
}

// ---------------------------------------------------------------------------
// Layer 0 GEMM: [px][32] x [64][32] -> bf16 NHWC, bias+lrelu. K=32 single step.
// ---------------------------------------------------------------------------
__global__ __launch_bounds__(256) void conv_first_mm(
    const unsigned short* __restrict__ ib, const unsigned short* __restrict__ wt,
    const float* __restrict__ bias, unsigned short* __restrict__ out)
{
    const int lane = threadIdx.x & 63, wid = threadIdx.x >> 6;
    const int m16 = lane & 15, kg = lane >> 4;

    s16x8 a[4];
    float4 bv[4];
#pragma unroll
    for (int mf = 0; mf < 4; ++mf) {
        a[mf] = *(const s16x8*)(wt + (mf * 16 + m16) * 32 + kg * 8);
        bv[mf] = *(const float4*)(bias + mf * 16 + kg * 4);
    }

    const int t0 = blockIdx.x * 16 + wid * 4;
#pragma unroll
    for (int t = 0; t < 4; ++t) {
        const size_t px0 = (size_t)(t0 + t) * 16;
        s16x8 bfr = *(const s16x8*)(ib + (px0 + m16) * 32 + kg * 8);
#pragma unroll
        for (int mf = 0; mf < 4; ++mf) {
            f32x4 c = (f32x4)(0.f);
            c = __builtin_amdgcn_mfma_f32_16x16x32_bf16(a[mf], bfr, c, 0, 0, 0);
            unsigned short pk[4];
#pragma unroll
            for (int e = 0; e < 4; ++e) {
                float v = c[e] + (&bv[mf].x)[e];
                v = v >= 0.f ? v : 0.1f * v;
                pk[e] = f2b(v);
            }
            *(ushort4*)(out + (px0 + m16) * NFC + mf * 16 + kg * 4) = *(ushort4*)pk;
        }
    }
}

// ---------------------------------------------------------------------------
// Main MFMA conv. Register-budget-clean version (round 8):
//  - A-frag pipeline depth 2 (distance 1) -> 32 VGPRs
//  - interior staging via global_load_lds DMA (0 VGPRs)
//  - border staging serial 1-deep (#pragma unroll 1, ~2 VGPRs)
//  - direct scatter epilogue stores (no LDS transpose)
// Live set ~142 regs -> fits __launch_bounds__(256,3) cap (~168), no spills.
// ---------------------------------------------------------------------------
template <int MFRAGS, bool PERB, bool BIAS, bool LRELU, bool NOISE, bool OUTF32>
__global__ __launch_bounds__(256, 3) void mconv(
    const unsigned short* __restrict__ in, const unsigned short* __restrict__ wt,
    const float* __restrict__ bias, const float* __restrict__ noise,
    const float* __restrict__ wnp, void* __restrict__ outv)
{
    constexpr int COP = MFRAGS * 16;
    __shared__ uint4 xs[18 * 18 * 8];            // 41472 B

    const int tid = threadIdx.x;
    // XCD-aware swizzle: 1024 blocks, 8 XCDs -> contiguous 128-block chunks
    const int flat = blockIdx.x;
    const int swz = (flat & 7) * 128 + (flat >> 3);
    const int b = swz >> 8, remb = swz & 255;
    const int th = remb >> 4, tw = remb & 15;
    const int h0 = th * 16, w0 = tw * 16;

    const int lane = tid & 63, wid = tid >> 6;
    const int m16 = lane & 15, kg = lane >> 4;

    const unsigned short* wbase = PERB ? wt + (size_t)b * 9 * COP * NFC : wt;
    const unsigned short* wlane = wbase + m16 * NFC + kg * 8;

    auto LOADA = [&](int g, s16x8* a) {
        const unsigned short* p = wlane + (size_t)(g >> 1) * (COP * NFC) + (g & 1) * 32;
#pragma unroll
        for (int mf = 0; mf < MFRAGS; ++mf)
            a[mf] = *(const s16x8*)(p + mf * 16 * NFC);
    };

    s16x8 abuf[2][MFRAGS];
    LOADA(0, abuf[0]);                 // in flight during staging

    const bool interior = (th > 0) && (th < 15) && (tw > 0) && (tw < 15);
    if (interior) {
        // 54 DMAs: i = row*3 + part; part -> j0 in {-1, 7, 9} (8 px each,
        // part 2 overlaps part 1 by 6 px: same data, same LDS addr, benign).
        for (int i = wid; i < 54; i += 4) {
            const int row = i / 3, part = i - row * 3;         // wave-uniform
            const int j0 = (part == 0) ? -1 : (part == 1) ? 7 : 9;
            const int gh = h0 + row - 1;
            const int j = j0 + (lane >> 3);                    // per-lane px
            const int gw = w0 + j;
            const int w = j + 1;                               // LDS w index
            // lane writes LDS slot sigma=lane&7 of pixel w; fetch global slot sigma^(w&7)
            const unsigned short* gp = in + (((size_t)b * HH + gh) * WW + gw) * NFC
                                          + ((lane & 7) ^ (w & 7)) * 8;
            uint4* lp = &xs[(size_t)(row * 18 + (j0 + 1)) * 8];
            __builtin_amdgcn_global_load_lds(
                (const GLOBAL_AS void*)gp, (LDS_AS void*)lp, 16, 0, 0);
        }
    } else {
        // border tiles: serial 1-deep load->ds_write (zero-padding), low regs
#pragma unroll 1
        for (int idx = tid; idx < 2592; idx += 256) {
            const int row = idx / 144, rem2 = idx - row * 144;
            const int w = rem2 >> 3, slot = rem2 & 7;
            const int gh = h0 + row - 1, gw = w0 + w - 1;
            uint4 u = make_uint4(0, 0, 0, 0);
            if ((unsigned)gh < HH && (unsigned)gw < WW)
                u = *(const uint4*)(in + (((size_t)b * HH + gh) * WW + gw) * NFC + slot * 8);
            xs[(row * 18 + w) * 8 + (slot ^ (w & 7))] = u;
        }
    }
    __syncthreads();

    f32x4 acc[MFRAGS][4];
#pragma unroll
    for (int mf = 0; mf < MFRAGS; ++mf)
#pragma unroll
        for (int r = 0; r < 4; ++r) acc[mf][r] = (f32x4)(0.f);

#pragma unroll
    for (int g = 0; g < 18; ++g) {
        const int tap = g >> 1, half = g & 1;
        const int kh = tap / 3, kw = tap - kh * 3;
        const int lw = m16 + kw;
        const int slot = (half * 4 + kg) ^ (lw & 7);

        if (g + 1 < 18) LOADA(g + 1, abuf[(g + 1) & 1]);   // depth-2, no alias

        s16x8 bf[4];
#pragma unroll
        for (int r = 0; r < 4; ++r) {
            const int lrow = wid * 4 + r + kh;
            bf[r] = *(const s16x8*)&xs[(lrow * 18 + lw) * 8 + slot];
        }
#pragma unroll
        for (int r = 0; r < 4; ++r)
#pragma unroll
            for (int mf = 0; mf < MFRAGS; ++mf)
                acc[mf][r] = __builtin_amdgcn_mfma_f32_16x16x32_bf16(
                    abuf[g & 1][mf], bf[r], acc[mf][r], 0, 0, 0);
    }

    // --- epilogue: direct stores (scatter ok; round-2 showed no write-amp) ---
    const int wcol = w0 + m16;
    const float wn = NOISE ? wnp[0] : 0.f;
#pragma unroll
    for (int r = 0; r < 4; ++r) {
        const int h = h0 + wid * 4 + r;
        float nz = 0.f;
        if (NOISE) nz = noise[((size_t)b * HH + h) * WW + wcol];
#pragma unroll
        for (int mf = 0; mf < MFRAGS; ++mf) {
            const int cob = mf * 16 + kg * 4;
            f32x4 v = acc[mf][r];
            float4 bvv = make_float4(0.f, 0.f, 0.f, 0.f);
            if (BIAS) bvv = *(const float4*)(bias + cob);
            float o[4];
#pragma unroll
            for (int e = 0; e < 4; ++e) {
                float t = v[e] + (BIAS ? (&bvv.x)[e] : 0.f);
                if (NOISE) t += wn * nz;
                if (LRELU) t = t >= 0.f ? t : 0.1f * t;
                o[e] = t;
            }
            if (OUTF32) {
                float* of = (float*)outv;
#pragma unroll
                for (int e = 0; e < 4; ++e) {
                    int co = cob + e;
                    if (co < 3)
                        of[(((size_t)b * 3 + co) * HH + h) * WW + wcol] = o[e];
                }
            } else {
                unsigned short pk[4];
#pragma unroll
                for (int e = 0; e < 4; ++e) pk[e] = f2b(o[e]);
                unsigned short* ob = (unsigned short*)outv;
                *(ushort4*)(ob + (((size_t)b * HH + h) * WW + wcol) * NFC + cob) = *(ushort4*)pk;
            }
        }
    }
}

// ---------------------------------------------------------------------------
extern "C" void kernel_launch(void* const* d_in, const int* in_sizes, int n_in,
                              void* d_out, int out_size, void* d_ws, size_t ws_size,
                              hipStream_t stream)
{
    auto F = [&](int i) { return (const float*)d_in[i]; };
    const float* x       = F(0);
    const float* emb     = F(1);
    const float* noise[3] = {F(2), F(3), F(4)};
    const float* w_first = F(5);  const float* b_first = F(6);
    const float* w_hr[5] = {F(7), F(9), F(11), F(13), F(15)};
    const float* b_hr[5] = {F(8), F(10), F(12), F(14), F(16)};
    const float* w_last  = F(17); const float* b_last = F(18);
    const float *m_mw[3], *m_mb[3], *m_w[3], *m_cw[3], *m_cb[3], *m_wn[3];
    for (int i = 0; i < 3; ++i) {
        int o = 19 + 6 * i;
        m_mw[i] = F(o); m_mb[i] = F(o + 1); m_w[i] = F(o + 2);
        m_cw[i] = F(o + 3); m_cb[i] = F(o + 4); m_wn[i] = F(o + 5);
    }

    // workspace layout (bf16 = unsigned short)
    const size_t ACT = (size_t)NB * HH * WW * NFC;
    const size_t NPX = (size_t)NB * HH * WW;
    unsigned short* act0 = (unsigned short*)d_ws;
    unsigned short* act1 = act0 + ACT;
    unsigned short* p = act1 + ACT;
    unsigned short* wmod[3];
    for (int i = 0; i < 3; ++i) { wmod[i] = p; p += (size_t)NB * 9 * NFC * NFC; }
    unsigned short* wfix[8];
    for (int i = 0; i < 8; ++i) { wfix[i] = p; p += (size_t)9 * NFC * NFC; }
    unsigned short* wlast = p;  p += 9 * 16 * NFC;
    unsigned short* wfirst = p; p += 64 * 32;
    unsigned short* ib = p;     // [NPX][32]

    // --- weight prep + im2col ---
    dim3 mg(NFC, NB);
    for (int i = 0; i < 3; ++i)
        modw_kernel<<<mg, NFC, 0, stream>>>(emb, m_mw[i], m_mb[i], m_w[i], wmod[i]);
    for (int i = 0; i < 3; ++i)
        fixw_kernel<<<(9 * 64 * 64 + 255) / 256, 256, 0, stream>>>(m_cw[i], wfix[i], 64, 64);
    for (int i = 0; i < 5; ++i)
        fixw_kernel<<<(9 * 64 * 64 + 255) / 256, 256, 0, stream>>>(w_hr[i], wfix[3 + i], 64, 64);
    fixw_kernel<<<(9 * 16 * 64 + 255) / 256, 256, 0, stream>>>(w_last, wlast, 3, 16);
    firstw_kernel<<<8, 256, 0, stream>>>(w_first, wfirst);
    im2col_kernel<<<NPX / 256, 256, 0, stream>>>(x, ib);

    // layer 0
    conv_first_mm<<<1024, 256, 0, stream>>>(ib, wfirst, b_first, act0);

    const int grid = 1024;   // flattened; mconv swizzles internally
    unsigned short* cur = act0;
    unsigned short* nxt = act1;
    auto swap = [&]() { unsigned short* t = cur; cur = nxt; nxt = t; };

    for (int i = 0; i < 3; ++i) {
        mconv<4, true, false, false, true, false>
            <<<grid, 256, 0, stream>>>(cur, wmod[i], nullptr, noise[i], m_wn[i], nxt);
        swap();
        mconv<4, false, true, true, false, false>
            <<<grid, 256, 0, stream>>>(cur, wfix[i], m_cb[i], nullptr, nullptr, nxt);
        swap();
        mconv<4, false, true, false, false, false>
            <<<grid, 256, 0, stream>>>(cur, wfix[3 + i], b_hr[i], nullptr, nullptr, nxt);
        swap();
    }
    mconv<4, false, true, false, false, false>
        <<<grid, 256, 0, stream>>>(cur, wfix[6], b_hr[3], nullptr, nullptr, nxt);
    swap();
    mconv<4, false, true, false, false, false>
        <<<grid, 256, 0, stream>>>(cur, wfix[7], b_hr[4], nullptr, nullptr, nxt);
    swap();
    mconv<1, false, true, false, false, true>
        <<<grid, 256, 0, stream>>>(cur, wlast, b_last, nullptr, nullptr, d_out);
}

// Round 9
// 504.576 us; speedup vs baseline: 1.7163x; 1.6522x over previous
//
#include <hip/hip_runtime.h>
#include <cstddef>

#define HH 256
#define WW 256
#define NB 4
#define NFC 64
#define EMBC 512

typedef short s16x8 __attribute__((ext_vector_type(8)));
typedef float f32x4 __attribute__((ext_vector_type(4)));

#define GLOBAL_AS __attribute__((address_space(1)))
#define LDS_AS __attribute__((address_space(3)))

static __device__ __forceinline__ unsigned short f2b(float f) {
    unsigned int u = __float_as_uint(f);
    u += 0x7FFFu + ((u >> 16) & 1u);
    return (unsigned short)(u >> 16);
}

// ---------------------------------------------------------------------------
// Modulated weights -> bf16 [b][tap][co][ci]. Block (co,b), 64 thr (ci).
// ---------------------------------------------------------------------------
__global__ void modw_kernel(const float* __restrict__ emb, const float* __restrict__ mw,
                            const float* __restrict__ mb, const float* __restrict__ bw,
                            unsigned short* __restrict__ outw)
{
    const int co = blockIdx.x, b = blockIdx.y;
    const int ci = threadIdx.x;

    const float* e = emb + (size_t)b * EMBC;
    const float* m = mw + (size_t)ci * EMBC;
    float s = mb[ci];
    for (int k = 0; k < EMBC; k += 4) {
        float4 ev = *(const float4*)(e + k);
        float4 mv = *(const float4*)(m + k);
        s += ev.x * mv.x + ev.y * mv.y + ev.z * mv.z + ev.w * mv.w;
    }

    float w[9];
    float ss = 0.f;
    const float* src = bw + ((size_t)co * NFC + ci) * 9;
#pragma unroll
    for (int k = 0; k < 9; ++k) {
        float v = (1.0f / 24.0f) * src[k] * s;
        w[k] = v;
        ss += v * v;
    }
#pragma unroll
    for (int off = 32; off; off >>= 1) ss += __shfl_xor(ss, off);
    float demod = rsqrtf(ss + 1e-8f);

#pragma unroll
    for (int k = 0; k < 9; ++k)
        outw[(((size_t)b * 9 + k) * NFC + co) * NFC + ci] = f2b(w[k] * demod);
}

// ---------------------------------------------------------------------------
// Fixed-weight transform: w[co][ci][3][3] f32 -> wt[tap][COP][64] bf16
// ---------------------------------------------------------------------------
__global__ void fixw_kernel(const float* __restrict__ w, unsigned short* __restrict__ wt,
                            int Cout, int COP)
{
    int idx = blockIdx.x * 256 + threadIdx.x;
    int total = 9 * COP * NFC;
    if (idx >= total) return;
    int k = idx / (COP * NFC);
    int rem = idx - k * (COP * NFC);
    int co = rem / NFC, ci = rem - co * NFC;
    float v = (co < Cout) ? w[((size_t)co * NFC + ci) * 9 + k] : 0.f;
    wt[idx] = f2b(v);
}

// ---------------------------------------------------------------------------
// conv_first weights: [64][3][3][3] f32 -> [64][32] bf16 (k = ci*9+kh*3+kw, pad)
// ---------------------------------------------------------------------------
__global__ void firstw_kernel(const float* __restrict__ w, unsigned short* __restrict__ wt)
{
    int idx = blockIdx.x * 256 + threadIdx.x;   // 64*32
    if (idx >= 64 * 32) return;
    int co = idx >> 5, k = idx & 31;
    wt[idx] = (k < 27) ? f2b(w[co * 27 + k]) : 0;
}

// ---------------------------------------------------------------------------
// im2col for layer 0: fp32 NCHW x -> bf16 [px][32], k = ci*9+kh*3+kw (27 real)
// ---------------------------------------------------------------------------
__global__ __launch_bounds__(256) void im2col_kernel(
    const float* __restrict__ x, unsigned short* __restrict__ ib)
{
    const int p = blockIdx.x * 256 + threadIdx.x;          // 0 .. 4*256*256-1
    const int b = p >> 16, hw = p & 0xFFFF;
    const int h = hw >> 8, w = hw & 255;

    unsigned short kv[32];
#pragma unroll
    for (int ci = 0; ci < 3; ++ci)
#pragma unroll
        for (int kh = 0; kh < 3; ++kh)
#pragma unroll
            for (int kw = 0; kw < 3; ++kw) {
                int gh = h + kh - 1, gw = w + kw - 1;
                float v = 0.f;
                if ((unsigned)gh < HH && (unsigned)gw < WW)
                    v = x[(((size_t)b * 3 + ci) * HH + gh) * WW + gw];
                kv[ci * 9 + kh * 3 + kw] = f2b(v);
            }
#pragma unroll
    for (int k = 27; k < 32; ++k) kv[k] = 0;

    unsigned short* op = ib + (size_t)p * 32;
#pragma unroll
    for (int q = 0; q < 4; ++q)
        *(uint4*)(op + q * 8) = *(const uint4*)(kv + q * 8);
}

// ---------------------------------------------------------------------------
// Layer 0 GEMM: [px][32] x [64][32] -> bf16 NHWC, bias+lrelu. K=32 single step.
// ---------------------------------------------------------------------------
__global__ __launch_bounds__(256) void conv_first_mm(
    const unsigned short* __restrict__ ib, const unsigned short* __restrict__ wt,
    const float* __restrict__ bias, unsigned short* __restrict__ out)
{
    const int lane = threadIdx.x & 63, wid = threadIdx.x >> 6;
    const int m16 = lane & 15, kg = lane >> 4;

    s16x8 a[4];
    float4 bv[4];
#pragma unroll
    for (int mf = 0; mf < 4; ++mf) {
        a[mf] = *(const s16x8*)(wt + (mf * 16 + m16) * 32 + kg * 8);
        bv[mf] = *(const float4*)(bias + mf * 16 + kg * 4);
    }

    const int t0 = blockIdx.x * 16 + wid * 4;
#pragma unroll
    for (int t = 0; t < 4; ++t) {
        const size_t px0 = (size_t)(t0 + t) * 16;
        s16x8 bfr = *(const s16x8*)(ib + (px0 + m16) * 32 + kg * 8);
#pragma unroll
        for (int mf = 0; mf < 4; ++mf) {
            f32x4 c = (f32x4)(0.f);
            c = __builtin_amdgcn_mfma_f32_16x16x32_bf16(a[mf], bfr, c, 0, 0, 0);
            unsigned short pk[4];
#pragma unroll
            for (int e = 0; e < 4; ++e) {
                float v = c[e] + (&bv[mf].x)[e];
                v = v >= 0.f ? v : 0.1f * v;
                pk[e] = f2b(v);
            }
            *(ushort4*)(out + (px0 + m16) * NFC + mf * 16 + kg * 4) = *(ushort4*)pk;
        }
    }
}

// ---------------------------------------------------------------------------
// Persistent MFMA conv (round 9):
//  - 256 blocks, 1/CU; block owns 4 tiles of one batch image (XCD-chunked)
//  - weights staged ONCE per block into LDS (XOR-swizzled via pre-swizzled
//    global DMA source); A-frags = ds_read_b128 at b128 bank floor
//  - activation tiles double-buffered: DMA tile k+1 overlaps compute of k
//  - one __syncthreads per tile (drains DMA + LDS)
// ---------------------------------------------------------------------------
template <int MFRAGS, bool PERB, bool BIAS, bool LRELU, bool NOISE, bool OUTF32>
__global__ __launch_bounds__(256, 1) void mconv(
    const unsigned short* __restrict__ in, const unsigned short* __restrict__ wt,
    const float* __restrict__ bias, const float* __restrict__ noise,
    const float* __restrict__ wnp, void* __restrict__ outv)
{
    constexpr int COP = MFRAGS * 16;
    constexpr int WELEM = 9 * COP * NFC;          // weight elements
    constexpr int NWDMA = WELEM * 2 / 1024;       // 72 (COP=64) / 18 (COP=16)
    __shared__ unsigned short wl[WELEM];          // 73728 B / 18432 B
    __shared__ uint4 xs[2][18 * 18 * 8];          // 2 x 41472 B

    const int tid = threadIdx.x;
    const int lane = tid & 63, wid = tid >> 6;
    const int m16 = lane & 15, kg = lane >> 4;

    // XCD-chunked persistent mapping: hw block -> logical n; 4 tiles per block
    const int hw = blockIdx.x;                    // 0..255
    const int n = (hw & 7) * 32 + (hw >> 3);      // logical 0..255
    const int b = n >> 6;                         // one batch image per block

    // ---- stage weights once (pre-swizzled source, linear LDS dest) ----
    const unsigned short* wsrc = PERB ? wt + (size_t)b * WELEM : wt;
    for (int i = wid; i < NWDMA; i += 4) {
        const unsigned short* gp = wsrc + i * 512 + (lane >> 3) * 64
                                   + (((lane & 7) ^ (lane >> 3)) << 3);
        __builtin_amdgcn_global_load_lds(
            (const GLOBAL_AS void*)gp, (LDS_AS void*)(wl + i * 512), 16, 0, 0);
    }

    // ---- tile stager (interior: DMA; border: serial reg path w/ zero-pad) ----
    auto stage_tile = [&](int tt, uint4* buf) {
        const int remb = tt & 255;
        const int th = remb >> 4, tw = remb & 15;
        const int h0 = th * 16, w0 = tw * 16;
        const bool interior = (th > 0) && (th < 15) && (tw > 0) && (tw < 15);
        if (interior) {
            for (int i = wid; i < 54; i += 4) {
                const int row = i / 3, part = i - row * 3;     // wave-uniform
                const int j0 = (part == 0) ? -1 : (part == 1) ? 7 : 9;
                const int gh = h0 + row - 1;
                const int j = j0 + (lane >> 3);                // per-lane px
                const int gw = w0 + j;
                const int w = j + 1;                           // LDS w index
                const unsigned short* gp = in + (((size_t)b * HH + gh) * WW + gw) * NFC
                                              + ((lane & 7) ^ (w & 7)) * 8;
                uint4* lp = buf + (size_t)(row * 18 + (j0 + 1)) * 8;
                __builtin_amdgcn_global_load_lds(
                    (const GLOBAL_AS void*)gp, (LDS_AS void*)lp, 16, 0, 0);
            }
        } else {
#pragma unroll 1
            for (int idx = tid; idx < 2592; idx += 256) {
                const int row = idx / 144, rem2 = idx - row * 144;
                const int w = rem2 >> 3, slot = rem2 & 7;
                const int gh = h0 + row - 1, gw = w0 + w - 1;
                uint4 u = make_uint4(0, 0, 0, 0);
                if ((unsigned)gh < HH && (unsigned)gw < WW)
                    u = *(const uint4*)(in + (((size_t)b * HH + gh) * WW + gw) * NFC + slot * 8);
                buf[(row * 18 + w) * 8 + (slot ^ (w & 7))] = u;
            }
        }
    };

    stage_tile(n * 4, xs[0]);
    __syncthreads();                              // drains weight + tile0 DMA

    const float wn = NOISE ? wnp[0] : 0.f;

#pragma unroll 1
    for (int k = 0; k < 4; ++k) {
        const int tt = n * 4 + k;
        const int remb = tt & 255;
        const int h0 = (remb >> 4) * 16, w0 = (remb & 15) * 16;
        const uint4* buf = xs[k & 1];

        if (k < 3) stage_tile(tt + 1, xs[(k + 1) & 1]);   // overlap with compute

        f32x4 acc[MFRAGS][4];
#pragma unroll
        for (int mf = 0; mf < MFRAGS; ++mf)
#pragma unroll
            for (int r = 0; r < 4; ++r) acc[mf][r] = (f32x4)(0.f);

#pragma unroll
        for (int g = 0; g < 18; ++g) {
            const int tap = g >> 1, half = g & 1;
            const int kh = tap / 3, kw = tap - kh * 3;
            const int lw = m16 + kw;
            const int slot = (half * 4 + kg) ^ (lw & 7);

            // A-frags from LDS weights (XOR-swizzled): row = tap*64+mf*16+m16
            s16x8 a[MFRAGS];
#pragma unroll
            for (int mf = 0; mf < MFRAGS; ++mf) {
                const int eoff = (tap * COP + mf * 16 + m16) * NFC
                                 + (((half * 4 + kg) * 8) ^ ((m16 & 7) << 3));
                a[mf] = *(const s16x8*)(wl + eoff);
            }
            s16x8 bf[4];
#pragma unroll
            for (int r = 0; r < 4; ++r) {
                const int lrow = wid * 4 + r + kh;
                bf[r] = *(const s16x8*)&buf[(lrow * 18 + lw) * 8 + slot];
            }
#pragma unroll
            for (int r = 0; r < 4; ++r)
#pragma unroll
                for (int mf = 0; mf < MFRAGS; ++mf)
                    acc[mf][r] = __builtin_amdgcn_mfma_f32_16x16x32_bf16(
                        a[mf], bf[r], acc[mf][r], 0, 0, 0);
        }

        // ---- epilogue ----
        const int wcol = w0 + m16;
#pragma unroll
        for (int r = 0; r < 4; ++r) {
            const int h = h0 + wid * 4 + r;
            float nz = 0.f;
            if (NOISE) nz = noise[((size_t)b * HH + h) * WW + wcol];
#pragma unroll
            for (int mf = 0; mf < MFRAGS; ++mf) {
                const int cob = mf * 16 + kg * 4;
                f32x4 v = acc[mf][r];
                float4 bvv = make_float4(0.f, 0.f, 0.f, 0.f);
                if (BIAS) bvv = *(const float4*)(bias + cob);
                float o[4];
#pragma unroll
                for (int e = 0; e < 4; ++e) {
                    float t = v[e] + (BIAS ? (&bvv.x)[e] : 0.f);
                    if (NOISE) t += wn * nz;
                    if (LRELU) t = t >= 0.f ? t : 0.1f * t;
                    o[e] = t;
                }
                if (OUTF32) {
                    float* of = (float*)outv;
#pragma unroll
                    for (int e = 0; e < 4; ++e) {
                        int co = cob + e;
                        if (co < 3)
                            of[(((size_t)b * 3 + co) * HH + h) * WW + wcol] = o[e];
                    }
                } else {
                    unsigned short pk[4];
#pragma unroll
                    for (int e = 0; e < 4; ++e) pk[e] = f2b(o[e]);
                    unsigned short* ob = (unsigned short*)outv;
                    *(ushort4*)(ob + (((size_t)b * HH + h) * WW + wcol) * NFC + cob) = *(ushort4*)pk;
                }
            }
        }
        __syncthreads();   // drains next-tile DMA; frees buf for k+2 staging
    }
}

// ---------------------------------------------------------------------------
extern "C" void kernel_launch(void* const* d_in, const int* in_sizes, int n_in,
                              void* d_out, int out_size, void* d_ws, size_t ws_size,
                              hipStream_t stream)
{
    auto F = [&](int i) { return (const float*)d_in[i]; };
    const float* x       = F(0);
    const float* emb     = F(1);
    const float* noise[3] = {F(2), F(3), F(4)};
    const float* w_first = F(5);  const float* b_first = F(6);
    const float* w_hr[5] = {F(7), F(9), F(11), F(13), F(15)};
    const float* b_hr[5] = {F(8), F(10), F(12), F(14), F(16)};
    const float* w_last  = F(17); const float* b_last = F(18);
    const float *m_mw[3], *m_mb[3], *m_w[3], *m_cw[3], *m_cb[3], *m_wn[3];
    for (int i = 0; i < 3; ++i) {
        int o = 19 + 6 * i;
        m_mw[i] = F(o); m_mb[i] = F(o + 1); m_w[i] = F(o + 2);
        m_cw[i] = F(o + 3); m_cb[i] = F(o + 4); m_wn[i] = F(o + 5);
    }

    // workspace layout (bf16 = unsigned short)
    const size_t ACT = (size_t)NB * HH * WW * NFC;
    const size_t NPX = (size_t)NB * HH * WW;
    unsigned short* act0 = (unsigned short*)d_ws;
    unsigned short* act1 = act0 + ACT;
    unsigned short* p = act1 + ACT;
    unsigned short* wmod[3];
    for (int i = 0; i < 3; ++i) { wmod[i] = p; p += (size_t)NB * 9 * NFC * NFC; }
    unsigned short* wfix[8];
    for (int i = 0; i < 8; ++i) { wfix[i] = p; p += (size_t)9 * NFC * NFC; }
    unsigned short* wlast = p;  p += 9 * 16 * NFC;
    unsigned short* wfirst = p; p += 64 * 32;
    unsigned short* ib = p;     // [NPX][32]

    // --- weight prep + im2col ---
    dim3 mg(NFC, NB);
    for (int i = 0; i < 3; ++i)
        modw_kernel<<<mg, NFC, 0, stream>>>(emb, m_mw[i], m_mb[i], m_w[i], wmod[i]);
    for (int i = 0; i < 3; ++i)
        fixw_kernel<<<(9 * 64 * 64 + 255) / 256, 256, 0, stream>>>(m_cw[i], wfix[i], 64, 64);
    for (int i = 0; i < 5; ++i)
        fixw_kernel<<<(9 * 64 * 64 + 255) / 256, 256, 0, stream>>>(w_hr[i], wfix[3 + i], 64, 64);
    fixw_kernel<<<(9 * 16 * 64 + 255) / 256, 256, 0, stream>>>(w_last, wlast, 3, 16);
    firstw_kernel<<<8, 256, 0, stream>>>(w_first, wfirst);
    im2col_kernel<<<NPX / 256, 256, 0, stream>>>(x, ib);

    // layer 0
    conv_first_mm<<<1024, 256, 0, stream>>>(ib, wfirst, b_first, act0);

    const int grid = 256;   // persistent: 1 block/CU, 4 tiles/block
    unsigned short* cur = act0;
    unsigned short* nxt = act1;
    auto swap = [&]() { unsigned short* t = cur; cur = nxt; nxt = t; };

    for (int i = 0; i < 3; ++i) {
        mconv<4, true, false, false, true, false>
            <<<grid, 256, 0, stream>>>(cur, wmod[i], nullptr, noise[i], m_wn[i], nxt);
        swap();
        mconv<4, false, true, true, false, false>
            <<<grid, 256, 0, stream>>>(cur, wfix[i], m_cb[i], nullptr, nullptr, nxt);
        swap();
        mconv<4, false, true, false, false, false>
            <<<grid, 256, 0, stream>>>(cur, wfix[3 + i], b_hr[i], nullptr, nullptr, nxt);
        swap();
    }
    mconv<4, false, true, false, false, false>
        <<<grid, 256, 0, stream>>>(cur, wfix[6], b_hr[3], nullptr, nullptr, nxt);
    swap();
    mconv<4, false, true, false, false, false>
        <<<grid, 256, 0, stream>>>(cur, wfix[7], b_hr[4], nullptr, nullptr, nxt);
    swap();
    mconv<1, false, true, false, false, true>
        <<<grid, 256, 0, stream>>>(cur, wlast, b_last, nullptr, nullptr, d_out);
}

// Round 10
// 463.234 us; speedup vs baseline: 1.8695x; 1.0892x over previous
//
#include <hip/hip_runtime.h>
#include <cstddef>

#define HH 256
#define WW 256
#define NB 4
#define NFC 64
#define EMBC 512

typedef short s16x8 __attribute__((ext_vector_type(8)));
typedef float f32x4 __attribute__((ext_vector_type(4)));

#define GLOBAL_AS __attribute__((address_space(1)))
#define LDS_AS __attribute__((address_space(3)))

static __device__ __forceinline__ unsigned short f2b(float f) {
    unsigned int u = __float_as_uint(f);
    u += 0x7FFFu + ((u >> 16) & 1u);
    return (unsigned short)(u >> 16);
}

// ---------------------------------------------------------------------------
// Modulated weights (all 3 mod blocks in one launch, blockIdx.z selects).
// -> bf16 [b][tap][co][ci]. Block (co,b), 64 thr (ci).
// ---------------------------------------------------------------------------
__global__ void modw3_kernel(
    const float* __restrict__ emb,
    const float* __restrict__ mw0, const float* __restrict__ mb0, const float* __restrict__ bw0,
    const float* __restrict__ mw1, const float* __restrict__ mb1, const float* __restrict__ bw1,
    const float* __restrict__ mw2, const float* __restrict__ mb2, const float* __restrict__ bw2,
    unsigned short* __restrict__ outw, size_t ostride)
{
    const int co = blockIdx.x, b = blockIdx.y;
    const int ci = threadIdx.x;
    const float *mw, *mb, *bw;
    switch (blockIdx.z) {                      // compile-time-ish select (SALU)
        case 0:  mw = mw0; mb = mb0; bw = bw0; break;
        case 1:  mw = mw1; mb = mb1; bw = bw1; break;
        default: mw = mw2; mb = mb2; bw = bw2; break;
    }

    const float* e = emb + (size_t)b * EMBC;
    const float* m = mw + (size_t)ci * EMBC;
    float s = mb[ci];
    for (int k = 0; k < EMBC; k += 4) {
        float4 ev = *(const float4*)(e + k);
        float4 mv = *(const float4*)(m + k);
        s += ev.x * mv.x + ev.y * mv.y + ev.z * mv.z + ev.w * mv.w;
    }

    float w[9];
    float ss = 0.f;
    const float* src = bw + ((size_t)co * NFC + ci) * 9;
#pragma unroll
    for (int k = 0; k < 9; ++k) {
        float v = (1.0f / 24.0f) * src[k] * s;
        w[k] = v;
        ss += v * v;
    }
#pragma unroll
    for (int off = 32; off; off >>= 1) ss += __shfl_xor(ss, off);
    float demod = rsqrtf(ss + 1e-8f);

    unsigned short* o = outw + (size_t)blockIdx.z * ostride;
#pragma unroll
    for (int k = 0; k < 9; ++k)
        o[(((size_t)b * 9 + k) * NFC + co) * NFC + ci] = f2b(w[k] * demod);
}

// ---------------------------------------------------------------------------
// Fixed-weight transform, 8 tensors in one launch (blockIdx.y selects; all
// contiguous in dst). w[64][64][3][3] f32 -> wt[tap][64][64] bf16.
// ---------------------------------------------------------------------------
__global__ void fixw8_kernel(
    const float* __restrict__ w0, const float* __restrict__ w1,
    const float* __restrict__ w2, const float* __restrict__ w3,
    const float* __restrict__ w4, const float* __restrict__ w5,
    const float* __restrict__ w6, const float* __restrict__ w7,
    unsigned short* __restrict__ wt)
{
    const int idx = blockIdx.x * 256 + threadIdx.x;     // < 9*64*64 = 36864
    const float* w;
    switch (blockIdx.y) {
        case 0: w = w0; break;  case 1: w = w1; break;
        case 2: w = w2; break;  case 3: w = w3; break;
        case 4: w = w4; break;  case 5: w = w5; break;
        case 6: w = w6; break;  default: w = w7; break;
    }
    const int k = idx / (NFC * NFC);
    const int rem = idx - k * (NFC * NFC);
    const int co = rem / NFC, ci = rem - co * NFC;
    wt[(size_t)blockIdx.y * 9 * NFC * NFC + idx] = f2b(w[((size_t)co * NFC + ci) * 9 + k]);
}

// ---------------------------------------------------------------------------
// Last-layer weights: [3][64][3][3] f32 -> wt[tap][16co(pad)][64] bf16
// ---------------------------------------------------------------------------
__global__ void fixw_last_kernel(const float* __restrict__ w, unsigned short* __restrict__ wt)
{
    int idx = blockIdx.x * 256 + threadIdx.x;
    if (idx >= 9 * 16 * NFC) return;
    int k = idx / (16 * NFC);
    int rem = idx - k * (16 * NFC);
    int co = rem / NFC, ci = rem - co * NFC;
    float v = (co < 3) ? w[((size_t)co * NFC + ci) * 9 + k] : 0.f;
    wt[idx] = f2b(v);
}

// ---------------------------------------------------------------------------
// conv_first weights: [64][3][3][3] f32 -> [64][32] bf16 (k = ci*9+kh*3+kw, pad)
// ---------------------------------------------------------------------------
__global__ void firstw_kernel(const float* __restrict__ w, unsigned short* __restrict__ wt)
{
    int idx = blockIdx.x * 256 + threadIdx.x;   // 64*32
    if (idx >= 64 * 32) return;
    int co = idx >> 5, k = idx & 31;
    wt[idx] = (k < 27) ? f2b(w[co * 27 + k]) : 0;
}

// ---------------------------------------------------------------------------
// Layer 0, fully fused (round 10): per 16x16 tile, stage 3-ch f32 halo in
// LDS, build im2col rows [256][36] in LDS, K=32 MFMA GEMM, bf16 NHWC out.
// Replaces the 268 MB im2col buffer round-trip.
// ---------------------------------------------------------------------------
__global__ __launch_bounds__(256) void conv_first_fused(
    const float* __restrict__ x, const unsigned short* __restrict__ wt,
    const float* __restrict__ bias, unsigned short* __restrict__ out)
{
    __shared__ float xf[3][18][20];              // 4320 B (pad 20)
    __shared__ unsigned short col[256][36];      // 18432 B (pad 36)

    const int tid = threadIdx.x;
    const int flat = blockIdx.x;
    const int swz = (flat & 7) * 128 + (flat >> 3);       // XCD swizzle
    const int b = swz >> 8, remb = swz & 255;
    const int h0 = (remb >> 4) * 16, w0 = (remb & 15) * 16;

    const int lane = tid & 63, wid = tid >> 6;
    const int m16 = lane & 15, kg = lane >> 4;

    // weights + bias into regs (L2/L3-hot; in flight during staging)
    s16x8 a[4];
    float4 bv[4];
#pragma unroll
    for (int mf = 0; mf < 4; ++mf) {
        a[mf] = *(const s16x8*)(wt + (mf * 16 + m16) * 32 + kg * 8);
        bv[mf] = *(const float4*)(bias + mf * 16 + kg * 4);
    }

    // --- stage x halo: 3 ch x 18 x 18 f32, zero-padded ---
#pragma unroll 1
    for (int idx = tid; idx < 972; idx += 256) {
        const int ci = idx / 324, rem2 = idx - ci * 324;
        const int row = rem2 / 18, colw = rem2 - row * 18;
        const int gh = h0 + row - 1, gw = w0 + colw - 1;
        float v = 0.f;
        if ((unsigned)gh < HH && (unsigned)gw < WW)
            v = x[(((size_t)b * 3 + ci) * HH + gh) * WW + gw];
        xf[ci][row][colw] = v;
    }
    __syncthreads();

    // --- build this thread's im2col row (px = tid) ---
    {
        const int h = tid >> 4, w = tid & 15;
        unsigned short kv[32];
#pragma unroll
        for (int ci = 0; ci < 3; ++ci)
#pragma unroll
            for (int kh = 0; kh < 3; ++kh)
#pragma unroll
                for (int kw = 0; kw < 3; ++kw)
                    kv[ci * 9 + kh * 3 + kw] = f2b(xf[ci][h + kh][w + kw]);
#pragma unroll
        for (int k = 27; k < 32; ++k) kv[k] = 0;
#pragma unroll
        for (int q = 0; q < 4; ++q)
            *(uint4*)&col[tid][q * 8] = *(const uint4*)(kv + q * 8);
    }
    __syncthreads();

    // --- GEMM: wave handles px = wid*64 .. +63 in 4 frags of 16 ---
#pragma unroll
    for (int t = 0; t < 4; ++t) {
        const int p = wid * 64 + t * 16 + m16;            // px in tile
        s16x8 bfr = *(const s16x8*)&col[p][kg * 8];
#pragma unroll
        for (int mf = 0; mf < 4; ++mf) {
            f32x4 c = (f32x4)(0.f);
            c = __builtin_amdgcn_mfma_f32_16x16x32_bf16(a[mf], bfr, c, 0, 0, 0);
            unsigned short pk[4];
#pragma unroll
            for (int e = 0; e < 4; ++e) {
                float v = c[e] + (&bv[mf].x)[e];
                v = v >= 0.f ? v : 0.1f * v;
                pk[e] = f2b(v);
            }
            const int h = h0 + (p >> 4), w = w0 + (p & 15);
            *(ushort4*)(out + (((size_t)b * HH + h) * WW + w) * NFC + mf * 16 + kg * 4)
                = *(ushort4*)pk;
        }
    }
}

// ---------------------------------------------------------------------------
// Persistent MFMA conv (unchanged from round 9):
//  - 256 blocks, 1/CU; block owns 4 tiles of one batch image (XCD-chunked)
//  - weights staged ONCE per block into LDS (XOR-swizzled DMA source)
//  - activation tiles double-buffered: DMA tile k+1 overlaps compute of k
// ---------------------------------------------------------------------------
template <int MFRAGS, bool PERB, bool BIAS, bool LRELU, bool NOISE, bool OUTF32>
__global__ __launch_bounds__(256, 1) void mconv(
    const unsigned short* __restrict__ in, const unsigned short* __restrict__ wt,
    const float* __restrict__ bias, const float* __restrict__ noise,
    const float* __restrict__ wnp, void* __restrict__ outv)
{
    constexpr int COP = MFRAGS * 16;
    constexpr int WELEM = 9 * COP * NFC;
    constexpr int NWDMA = WELEM * 2 / 1024;
    __shared__ unsigned short wl[WELEM];
    __shared__ uint4 xs[2][18 * 18 * 8];

    const int tid = threadIdx.x;
    const int lane = tid & 63, wid = tid >> 6;
    const int m16 = lane & 15, kg = lane >> 4;

    const int hw = blockIdx.x;                    // 0..255
    const int n = (hw & 7) * 32 + (hw >> 3);      // logical 0..255
    const int b = n >> 6;

    const unsigned short* wsrc = PERB ? wt + (size_t)b * WELEM : wt;
    for (int i = wid; i < NWDMA; i += 4) {
        const unsigned short* gp = wsrc + i * 512 + (lane >> 3) * 64
                                   + (((lane & 7) ^ (lane >> 3)) << 3);
        __builtin_amdgcn_global_load_lds(
            (const GLOBAL_AS void*)gp, (LDS_AS void*)(wl + i * 512), 16, 0, 0);
    }

    auto stage_tile = [&](int tt, uint4* buf) {
        const int remb = tt & 255;
        const int th = remb >> 4, tw = remb & 15;
        const int h0 = th * 16, w0 = tw * 16;
        const bool interior = (th > 0) && (th < 15) && (tw > 0) && (tw < 15);
        if (interior) {
            for (int i = wid; i < 54; i += 4) {
                const int row = i / 3, part = i - row * 3;
                const int j0 = (part == 0) ? -1 : (part == 1) ? 7 : 9;
                const int gh = h0 + row - 1;
                const int j = j0 + (lane >> 3);
                const int gw = w0 + j;
                const int w = j + 1;
                const unsigned short* gp = in + (((size_t)b * HH + gh) * WW + gw) * NFC
                                              + ((lane & 7) ^ (w & 7)) * 8;
                uint4* lp = buf + (size_t)(row * 18 + (j0 + 1)) * 8;
                __builtin_amdgcn_global_load_lds(
                    (const GLOBAL_AS void*)gp, (LDS_AS void*)lp, 16, 0, 0);
            }
        } else {
#pragma unroll 1
            for (int idx = tid; idx < 2592; idx += 256) {
                const int row = idx / 144, rem2 = idx - row * 144;
                const int w = rem2 >> 3, slot = rem2 & 7;
                const int gh = h0 + row - 1, gw = w0 + w - 1;
                uint4 u = make_uint4(0, 0, 0, 0);
                if ((unsigned)gh < HH && (unsigned)gw < WW)
                    u = *(const uint4*)(in + (((size_t)b * HH + gh) * WW + gw) * NFC + slot * 8);
                buf[(row * 18 + w) * 8 + (slot ^ (w & 7))] = u;
            }
        }
    };

    stage_tile(n * 4, xs[0]);
    __syncthreads();

    const float wn = NOISE ? wnp[0] : 0.f;

#pragma unroll 1
    for (int k = 0; k < 4; ++k) {
        const int tt = n * 4 + k;
        const int remb = tt & 255;
        const int h0 = (remb >> 4) * 16, w0 = (remb & 15) * 16;
        const uint4* buf = xs[k & 1];

        if (k < 3) stage_tile(tt + 1, xs[(k + 1) & 1]);

        f32x4 acc[MFRAGS][4];
#pragma unroll
        for (int mf = 0; mf < MFRAGS; ++mf)
#pragma unroll
            for (int r = 0; r < 4; ++r) acc[mf][r] = (f32x4)(0.f);

#pragma unroll
        for (int g = 0; g < 18; ++g) {
            const int tap = g >> 1, half = g & 1;
            const int kh = tap / 3, kw = tap - kh * 3;
            const int lw = m16 + kw;
            const int slot = (half * 4 + kg) ^ (lw & 7);

            s16x8 a[MFRAGS];
#pragma unroll
            for (int mf = 0; mf < MFRAGS; ++mf) {
                const int eoff = (tap * COP + mf * 16 + m16) * NFC
                                 + (((half * 4 + kg) * 8) ^ ((m16 & 7) << 3));
                a[mf] = *(const s16x8*)(wl + eoff);
            }
            s16x8 bf[4];
#pragma unroll
            for (int r = 0; r < 4; ++r) {
                const int lrow = wid * 4 + r + kh;
                bf[r] = *(const s16x8*)&buf[(lrow * 18 + lw) * 8 + slot];
            }
#pragma unroll
            for (int r = 0; r < 4; ++r)
#pragma unroll
                for (int mf = 0; mf < MFRAGS; ++mf)
                    acc[mf][r] = __builtin_amdgcn_mfma_f32_16x16x32_bf16(
                        a[mf], bf[r], acc[mf][r], 0, 0, 0);
        }

        const int wcol = w0 + m16;
#pragma unroll
        for (int r = 0; r < 4; ++r) {
            const int h = h0 + wid * 4 + r;
            float nz = 0.f;
            if (NOISE) nz = noise[((size_t)b * HH + h) * WW + wcol];
#pragma unroll
            for (int mf = 0; mf < MFRAGS; ++mf) {
                const int cob = mf * 16 + kg * 4;
                f32x4 v = acc[mf][r];
                float4 bvv = make_float4(0.f, 0.f, 0.f, 0.f);
                if (BIAS) bvv = *(const float4*)(bias + cob);
                float o[4];
#pragma unroll
                for (int e = 0; e < 4; ++e) {
                    float t = v[e] + (BIAS ? (&bvv.x)[e] : 0.f);
                    if (NOISE) t += wn * nz;
                    if (LRELU) t = t >= 0.f ? t : 0.1f * t;
                    o[e] = t;
                }
                if (OUTF32) {
                    float* of = (float*)outv;
#pragma unroll
                    for (int e = 0; e < 4; ++e) {
                        int co = cob + e;
                        if (co < 3)
                            of[(((size_t)b * 3 + co) * HH + h) * WW + wcol] = o[e];
                    }
                } else {
                    unsigned short pk[4];
#pragma unroll
                    for (int e = 0; e < 4; ++e) pk[e] = f2b(o[e]);
                    unsigned short* ob = (unsigned short*)outv;
                    *(ushort4*)(ob + (((size_t)b * HH + h) * WW + wcol) * NFC + cob) = *(ushort4*)pk;
                }
            }
        }
        __syncthreads();
    }
}

// ---------------------------------------------------------------------------
extern "C" void kernel_launch(void* const* d_in, const int* in_sizes, int n_in,
                              void* d_out, int out_size, void* d_ws, size_t ws_size,
                              hipStream_t stream)
{
    auto F = [&](int i) { return (const float*)d_in[i]; };
    const float* x       = F(0);
    const float* emb     = F(1);
    const float* noise[3] = {F(2), F(3), F(4)};
    const float* w_first = F(5);  const float* b_first = F(6);
    const float* w_hr[5] = {F(7), F(9), F(11), F(13), F(15)};
    const float* b_hr[5] = {F(8), F(10), F(12), F(14), F(16)};
    const float* w_last  = F(17); const float* b_last = F(18);
    const float *m_mw[3], *m_mb[3], *m_w[3], *m_cw[3], *m_cb[3], *m_wn[3];
    for (int i = 0; i < 3; ++i) {
        int o = 19 + 6 * i;
        m_mw[i] = F(o); m_mb[i] = F(o + 1); m_w[i] = F(o + 2);
        m_cw[i] = F(o + 3); m_cb[i] = F(o + 4); m_wn[i] = F(o + 5);
    }

    // workspace layout (bf16 = unsigned short)
    const size_t ACT  = (size_t)NB * HH * WW * NFC;
    const size_t MODW = (size_t)NB * 9 * NFC * NFC;
    const size_t FIXW = (size_t)9 * NFC * NFC;
    unsigned short* act0 = (unsigned short*)d_ws;
    unsigned short* act1 = act0 + ACT;
    unsigned short* wmod = act1 + ACT;            // 3 contiguous MODW blocks
    unsigned short* wfix = wmod + 3 * MODW;       // 8 contiguous FIXW blocks
    unsigned short* wlast = wfix + 8 * FIXW;
    unsigned short* wfirst = wlast + 9 * 16 * NFC;

    // --- weight prep (batched) ---
    modw3_kernel<<<dim3(NFC, NB, 3), NFC, 0, stream>>>(
        emb, m_mw[0], m_mb[0], m_w[0], m_mw[1], m_mb[1], m_w[1],
        m_mw[2], m_mb[2], m_w[2], wmod, MODW);
    fixw8_kernel<<<dim3(144, 8), 256, 0, stream>>>(
        m_cw[0], m_cw[1], m_cw[2], w_hr[0], w_hr[1], w_hr[2], w_hr[3], w_hr[4], wfix);
    fixw_last_kernel<<<(9 * 16 * 64 + 255) / 256, 256, 0, stream>>>(w_last, wlast);
    firstw_kernel<<<8, 256, 0, stream>>>(w_first, wfirst);

    // layer 0 (fused im2col + GEMM)
    conv_first_fused<<<1024, 256, 0, stream>>>(x, wfirst, b_first, act0);

    const int grid = 256;   // persistent: 1 block/CU, 4 tiles/block
    unsigned short* cur = act0;
    unsigned short* nxt = act1;
    auto swap = [&]() { unsigned short* t = cur; cur = nxt; nxt = t; };

    // fixw order: cl0,cl1,cl2,hr1..hr5 (matches fixw8 arg order)
    for (int i = 0; i < 3; ++i) {
        mconv<4, true, false, false, true, false>
            <<<grid, 256, 0, stream>>>(cur, wmod + i * MODW, nullptr, noise[i], m_wn[i], nxt);
        swap();
        mconv<4, false, true, true, false, false>
            <<<grid, 256, 0, stream>>>(cur, wfix + i * FIXW, m_cb[i], nullptr, nullptr, nxt);
        swap();
        mconv<4, false, true, false, false, false>
            <<<grid, 256, 0, stream>>>(cur, wfix + (3 + i) * FIXW, b_hr[i], nullptr, nullptr, nxt);
        swap();
    }
    mconv<4, false, true, false, false, false>
        <<<grid, 256, 0, stream>>>(cur, wfix + 6 * FIXW, b_hr[3], nullptr, nullptr, nxt);
    swap();
    mconv<4, false, true, false, false, false>
        <<<grid, 256, 0, stream>>>(cur, wfix + 7 * FIXW, b_hr[4], nullptr, nullptr, nxt);
    swap();
    mconv<1, false, true, false, false, true>
        <<<grid, 256, 0, stream>>>(cur, wlast, b_last, nullptr, nullptr, d_out);
}

// Round 11
// 354.616 us; speedup vs baseline: 2.4421x; 1.3063x over previous
//
#include <hip/hip_runtime.h>
#include <cstddef>

#define HH 256
#define WW 256
#define NB 4
#define NFC 64
#define EMBC 512

typedef short s16x8 __attribute__((ext_vector_type(8)));
typedef float f32x4 __attribute__((ext_vector_type(4)));

#define GLOBAL_AS __attribute__((address_space(1)))
#define LDS_AS __attribute__((address_space(3)))

static __device__ __forceinline__ unsigned short f2b(float f) {
    unsigned int u = __float_as_uint(f);
    u += 0x7FFFu + ((u >> 16) & 1u);
    return (unsigned short)(u >> 16);
}

// ---------------------------------------------------------------------------
// Modulated weights (3 blocks in one launch) -> bf16 [b][tap][co][ci]
// ---------------------------------------------------------------------------
__global__ void modw3_kernel(
    const float* __restrict__ emb,
    const float* __restrict__ mw0, const float* __restrict__ mb0, const float* __restrict__ bw0,
    const float* __restrict__ mw1, const float* __restrict__ mb1, const float* __restrict__ bw1,
    const float* __restrict__ mw2, const float* __restrict__ mb2, const float* __restrict__ bw2,
    unsigned short* __restrict__ outw, size_t ostride)
{
    const int co = blockIdx.x, b = blockIdx.y;
    const int ci = threadIdx.x;
    const float *mw, *mb, *bw;
    switch (blockIdx.z) {
        case 0:  mw = mw0; mb = mb0; bw = bw0; break;
        case 1:  mw = mw1; mb = mb1; bw = bw1; break;
        default: mw = mw2; mb = mb2; bw = bw2; break;
    }

    const float* e = emb + (size_t)b * EMBC;
    const float* m = mw + (size_t)ci * EMBC;
    float s = mb[ci];
    for (int k = 0; k < EMBC; k += 4) {
        float4 ev = *(const float4*)(e + k);
        float4 mv = *(const float4*)(m + k);
        s += ev.x * mv.x + ev.y * mv.y + ev.z * mv.z + ev.w * mv.w;
    }

    float w[9];
    float ss = 0.f;
    const float* src = bw + ((size_t)co * NFC + ci) * 9;
#pragma unroll
    for (int k = 0; k < 9; ++k) {
        float v = (1.0f / 24.0f) * src[k] * s;
        w[k] = v;
        ss += v * v;
    }
#pragma unroll
    for (int off = 32; off; off >>= 1) ss += __shfl_xor(ss, off);
    float demod = rsqrtf(ss + 1e-8f);

    unsigned short* o = outw + (size_t)blockIdx.z * ostride;
#pragma unroll
    for (int k = 0; k < 9; ++k)
        o[(((size_t)b * 9 + k) * NFC + co) * NFC + ci] = f2b(w[k] * demod);
}

// ---------------------------------------------------------------------------
// Fixed-weight transform, 8 tensors in one launch.
// ---------------------------------------------------------------------------
__global__ void fixw8_kernel(
    const float* __restrict__ w0, const float* __restrict__ w1,
    const float* __restrict__ w2, const float* __restrict__ w3,
    const float* __restrict__ w4, const float* __restrict__ w5,
    const float* __restrict__ w6, const float* __restrict__ w7,
    unsigned short* __restrict__ wt)
{
    const int idx = blockIdx.x * 256 + threadIdx.x;
    const float* w;
    switch (blockIdx.y) {
        case 0: w = w0; break;  case 1: w = w1; break;
        case 2: w = w2; break;  case 3: w = w3; break;
        case 4: w = w4; break;  case 5: w = w5; break;
        case 6: w = w6; break;  default: w = w7; break;
    }
    const int k = idx / (NFC * NFC);
    const int rem = idx - k * (NFC * NFC);
    const int co = rem / NFC, ci = rem - co * NFC;
    wt[(size_t)blockIdx.y * 9 * NFC * NFC + idx] = f2b(w[((size_t)co * NFC + ci) * 9 + k]);
}

// ---------------------------------------------------------------------------
__global__ void fixw_last_kernel(const float* __restrict__ w, unsigned short* __restrict__ wt)
{
    int idx = blockIdx.x * 256 + threadIdx.x;
    if (idx >= 9 * 16 * NFC) return;
    int k = idx / (16 * NFC);
    int rem = idx - k * (16 * NFC);
    int co = rem / NFC, ci = rem - co * NFC;
    float v = (co < 3) ? w[((size_t)co * NFC + ci) * 9 + k] : 0.f;
    wt[idx] = f2b(v);
}

// ---------------------------------------------------------------------------
__global__ void firstw_kernel(const float* __restrict__ w, unsigned short* __restrict__ wt)
{
    int idx = blockIdx.x * 256 + threadIdx.x;   // 64*32
    if (idx >= 64 * 32) return;
    int co = idx >> 5, k = idx & 31;
    wt[idx] = (k < 27) ? f2b(w[co * 27 + k]) : 0;
}

// ---------------------------------------------------------------------------
// Layer 0 fused: halo->LDS, im2col->LDS, K=32 MFMA, bf16 NHWC out.
// ---------------------------------------------------------------------------
__global__ __launch_bounds__(256) void conv_first_fused(
    const float* __restrict__ x, const unsigned short* __restrict__ wt,
    const float* __restrict__ bias, unsigned short* __restrict__ out)
{
    __shared__ float xf[3][18][20];
    __shared__ unsigned short col[256][36];

    const int tid = threadIdx.x;
    const int flat = blockIdx.x;
    const int swz = (flat & 7) * 128 + (flat >> 3);
    const int b = swz >> 8, remb = swz & 255;
    const int h0 = (remb >> 4) * 16, w0 = (remb & 15) * 16;

    const int lane = tid & 63, wid = tid >> 6;
    const int m16 = lane & 15, kg = lane >> 4;

    s16x8 a[4];
    float4 bv[4];
#pragma unroll
    for (int mf = 0; mf < 4; ++mf) {
        a[mf] = *(const s16x8*)(wt + (mf * 16 + m16) * 32 + kg * 8);
        bv[mf] = *(const float4*)(bias + mf * 16 + kg * 4);
    }

#pragma unroll 1
    for (int idx = tid; idx < 972; idx += 256) {
        const int ci = idx / 324, rem2 = idx - ci * 324;
        const int row = rem2 / 18, colw = rem2 - row * 18;
        const int gh = h0 + row - 1, gw = w0 + colw - 1;
        float v = 0.f;
        if ((unsigned)gh < HH && (unsigned)gw < WW)
            v = x[(((size_t)b * 3 + ci) * HH + gh) * WW + gw];
        xf[ci][row][colw] = v;
    }
    __syncthreads();

    {
        const int h = tid >> 4, w = tid & 15;
        unsigned short kv[32];
#pragma unroll
        for (int ci = 0; ci < 3; ++ci)
#pragma unroll
            for (int kh = 0; kh < 3; ++kh)
#pragma unroll
                for (int kw = 0; kw < 3; ++kw)
                    kv[ci * 9 + kh * 3 + kw] = f2b(xf[ci][h + kh][w + kw]);
#pragma unroll
        for (int k = 27; k < 32; ++k) kv[k] = 0;
#pragma unroll
        for (int q = 0; q < 4; ++q)
            *(uint4*)&col[tid][q * 8] = *(const uint4*)(kv + q * 8);
    }
    __syncthreads();

#pragma unroll
    for (int t = 0; t < 4; ++t) {
        const int p = wid * 64 + t * 16 + m16;
        s16x8 bfr = *(const s16x8*)&col[p][kg * 8];
#pragma unroll
        for (int mf = 0; mf < 4; ++mf) {
            f32x4 c = (f32x4)(0.f);
            c = __builtin_amdgcn_mfma_f32_16x16x32_bf16(a[mf], bfr, c, 0, 0, 0);
            unsigned short pk[4];
#pragma unroll
            for (int e = 0; e < 4; ++e) {
                float v = c[e] + (&bv[mf].x)[e];
                v = v >= 0.f ? v : 0.1f * v;
                pk[e] = f2b(v);
            }
            const int h = h0 + (p >> 4), w = w0 + (p & 15);
            *(ushort4*)(out + (((size_t)b * HH + h) * WW + w) * NFC + mf * 16 + kg * 4)
                = *(ushort4*)pk;
        }
    }
}

// ---------------------------------------------------------------------------
// Persistent MFMA conv v2 (round 11): 512 threads = 8 waves (2/SIMD).
// Row-split: wave owns 2 rows x all 64 co (acc[4][2]).
// Explicit g+1 A/B prefetch (parity regs); weights in LDS; tiles dbuf'd.
// ---------------------------------------------------------------------------
template <int MFRAGS, bool PERB, bool BIAS, bool LRELU, bool NOISE, bool OUTF32>
__global__ __launch_bounds__(512, 1) void mconv(
    const unsigned short* __restrict__ in, const unsigned short* __restrict__ wt,
    const float* __restrict__ bias, const float* __restrict__ noise,
    const float* __restrict__ wnp, void* __restrict__ outv)
{
    constexpr int COP = MFRAGS * 16;
    constexpr int WELEM = 9 * COP * NFC;
    constexpr int NWDMA = WELEM * 2 / 1024;
    __shared__ unsigned short wl[WELEM];          // 73728 B (COP=64)
    __shared__ uint4 xs[2][18 * 18 * 8];          // 82944 B

    const int tid = threadIdx.x;
    const int lane = tid & 63, wid = tid >> 6;    // wid 0..7
    const int m16 = lane & 15, kg = lane >> 4;

    const int hw = blockIdx.x;                    // 0..255
    const int n = (hw & 7) * 32 + (hw >> 3);      // XCD-chunked logical id
    const int b = n >> 6;

    // ---- stage weights once ----
    const unsigned short* wsrc = PERB ? wt + (size_t)b * WELEM : wt;
    for (int i = wid; i < NWDMA; i += 8) {
        const unsigned short* gp = wsrc + i * 512 + (lane >> 3) * 64
                                   + (((lane & 7) ^ (lane >> 3)) << 3);
        __builtin_amdgcn_global_load_lds(
            (const GLOBAL_AS void*)gp, (LDS_AS void*)(wl + i * 512), 16, 0, 0);
    }

    auto stage_tile = [&](int tt, uint4* buf) {
        const int remb = tt & 255;
        const int th = remb >> 4, tw = remb & 15;
        const int h0 = th * 16, w0 = tw * 16;
        const bool interior = (th > 0) && (th < 15) && (tw > 0) && (tw < 15);
        if (interior) {
            for (int i = wid; i < 54; i += 8) {
                const int row = i / 3, part = i - row * 3;
                const int j0 = (part == 0) ? -1 : (part == 1) ? 7 : 9;
                const int gh = h0 + row - 1;
                const int j = j0 + (lane >> 3);
                const int gw = w0 + j;
                const int w = j + 1;
                const unsigned short* gp = in + (((size_t)b * HH + gh) * WW + gw) * NFC
                                              + ((lane & 7) ^ (w & 7)) * 8;
                uint4* lp = buf + (size_t)(row * 18 + (j0 + 1)) * 8;
                __builtin_amdgcn_global_load_lds(
                    (const GLOBAL_AS void*)gp, (LDS_AS void*)lp, 16, 0, 0);
            }
        } else {
#pragma unroll 1
            for (int idx = tid; idx < 2592; idx += 512) {
                const int row = idx / 144, rem2 = idx - row * 144;
                const int w = rem2 >> 3, slot = rem2 & 7;
                const int gh = h0 + row - 1, gw = w0 + w - 1;
                uint4 u = make_uint4(0, 0, 0, 0);
                if ((unsigned)gh < HH && (unsigned)gw < WW)
                    u = *(const uint4*)(in + (((size_t)b * HH + gh) * WW + gw) * NFC + slot * 8);
                buf[(row * 18 + w) * 8 + (slot ^ (w & 7))] = u;
            }
        }
    };

    stage_tile(n * 4, xs[0]);
    __syncthreads();

    const float wn = NOISE ? wnp[0] : 0.f;

#pragma unroll 1
    for (int k = 0; k < 4; ++k) {
        const int tt = n * 4 + k;
        const int remb = tt & 255;
        const int h0 = (remb >> 4) * 16, w0 = (remb & 15) * 16;
        const uint4* buf = xs[k & 1];

        if (k < 3) stage_tile(tt + 1, xs[(k + 1) & 1]);

        f32x4 acc[MFRAGS][2];
#pragma unroll
        for (int mf = 0; mf < MFRAGS; ++mf)
#pragma unroll
            for (int r = 0; r < 2; ++r) acc[mf][r] = (f32x4)(0.f);

        // parity-indexed prefetch regs (compile-time after unroll)
        s16x8 abuf[2][MFRAGS];
        s16x8 bbuf[2][2];

        auto LOADG = [&](int g, int par) {
            const int tap = g >> 1, half = g & 1;
            const int kh = tap / 3, kw = tap - kh * 3;
            const int lw = m16 + kw;
            const int slot = (half * 4 + kg) ^ (lw & 7);
#pragma unroll
            for (int mf = 0; mf < MFRAGS; ++mf) {
                const int eoff = (tap * COP + mf * 16 + m16) * NFC
                                 + (((half * 4 + kg) * 8) ^ ((m16 & 7) << 3));
                abuf[par][mf] = *(const s16x8*)(wl + eoff);
            }
#pragma unroll
            for (int r = 0; r < 2; ++r) {
                const int lrow = wid * 2 + r + kh;
                bbuf[par][r] = *(const s16x8*)&buf[(lrow * 18 + lw) * 8 + slot];
            }
        };

        LOADG(0, 0);
#pragma unroll
        for (int g = 0; g < 18; ++g) {
            if (g + 1 < 18) LOADG(g + 1, (g + 1) & 1);
#pragma unroll
            for (int r = 0; r < 2; ++r)
#pragma unroll
                for (int mf = 0; mf < MFRAGS; ++mf)
                    acc[mf][r] = __builtin_amdgcn_mfma_f32_16x16x32_bf16(
                        abuf[g & 1][mf], bbuf[g & 1][r], acc[mf][r], 0, 0, 0);
        }

        // ---- epilogue: wave owns rows wid*2, wid*2+1 ----
        const int wcol = w0 + m16;
#pragma unroll
        for (int r = 0; r < 2; ++r) {
            const int h = h0 + wid * 2 + r;
            float nz = 0.f;
            if (NOISE) nz = noise[((size_t)b * HH + h) * WW + wcol];
#pragma unroll
            for (int mf = 0; mf < MFRAGS; ++mf) {
                const int cob = mf * 16 + kg * 4;
                f32x4 v = acc[mf][r];
                float4 bvv = make_float4(0.f, 0.f, 0.f, 0.f);
                if (BIAS) bvv = *(const float4*)(bias + cob);
                float o[4];
#pragma unroll
                for (int e = 0; e < 4; ++e) {
                    float t = v[e] + (BIAS ? (&bvv.x)[e] : 0.f);
                    if (NOISE) t += wn * nz;
                    if (LRELU) t = t >= 0.f ? t : 0.1f * t;
                    o[e] = t;
                }
                if (OUTF32) {
                    float* of = (float*)outv;
#pragma unroll
                    for (int e = 0; e < 4; ++e) {
                        int co = cob + e;
                        if (co < 3)
                            of[(((size_t)b * 3 + co) * HH + h) * WW + wcol] = o[e];
                    }
                } else {
                    unsigned short pk[4];
#pragma unroll
                    for (int e = 0; e < 4; ++e) pk[e] = f2b(o[e]);
                    unsigned short* ob = (unsigned short*)outv;
                    *(ushort4*)(ob + (((size_t)b * HH + h) * WW + wcol) * NFC + cob) = *(ushort4*)pk;
                }
            }
        }
        __syncthreads();
    }
}

// ---------------------------------------------------------------------------
extern "C" void kernel_launch(void* const* d_in, const int* in_sizes, int n_in,
                              void* d_out, int out_size, void* d_ws, size_t ws_size,
                              hipStream_t stream)
{
    auto F = [&](int i) { return (const float*)d_in[i]; };
    const float* x       = F(0);
    const float* emb     = F(1);
    const float* noise[3] = {F(2), F(3), F(4)};
    const float* w_first = F(5);  const float* b_first = F(6);
    const float* w_hr[5] = {F(7), F(9), F(11), F(13), F(15)};
    const float* b_hr[5] = {F(8), F(10), F(12), F(14), F(16)};
    const float* w_last  = F(17); const float* b_last = F(18);
    const float *m_mw[3], *m_mb[3], *m_w[3], *m_cw[3], *m_cb[3], *m_wn[3];
    for (int i = 0; i < 3; ++i) {
        int o = 19 + 6 * i;
        m_mw[i] = F(o); m_mb[i] = F(o + 1); m_w[i] = F(o + 2);
        m_cw[i] = F(o + 3); m_cb[i] = F(o + 4); m_wn[i] = F(o + 5);
    }

    const size_t ACT  = (size_t)NB * HH * WW * NFC;
    const size_t MODW = (size_t)NB * 9 * NFC * NFC;
    const size_t FIXW = (size_t)9 * NFC * NFC;
    unsigned short* act0 = (unsigned short*)d_ws;
    unsigned short* act1 = act0 + ACT;
    unsigned short* wmod = act1 + ACT;
    unsigned short* wfix = wmod + 3 * MODW;
    unsigned short* wlast = wfix + 8 * FIXW;
    unsigned short* wfirst = wlast + 9 * 16 * NFC;

    modw3_kernel<<<dim3(NFC, NB, 3), NFC, 0, stream>>>(
        emb, m_mw[0], m_mb[0], m_w[0], m_mw[1], m_mb[1], m_w[1],
        m_mw[2], m_mb[2], m_w[2], wmod, MODW);
    fixw8_kernel<<<dim3(144, 8), 256, 0, stream>>>(
        m_cw[0], m_cw[1], m_cw[2], w_hr[0], w_hr[1], w_hr[2], w_hr[3], w_hr[4], wfix);
    fixw_last_kernel<<<(9 * 16 * 64 + 255) / 256, 256, 0, stream>>>(w_last, wlast);
    firstw_kernel<<<8, 256, 0, stream>>>(w_first, wfirst);

    conv_first_fused<<<1024, 256, 0, stream>>>(x, wfirst, b_first, act0);

    const int grid = 256;
    unsigned short* cur = act0;
    unsigned short* nxt = act1;
    auto swap = [&]() { unsigned short* t = cur; cur = nxt; nxt = t; };

    for (int i = 0; i < 3; ++i) {
        mconv<4, true, false, false, true, false>
            <<<grid, 512, 0, stream>>>(cur, wmod + i * MODW, nullptr, noise[i], m_wn[i], nxt);
        swap();
        mconv<4, false, true, true, false, false>
            <<<grid, 512, 0, stream>>>(cur, wfix + i * FIXW, m_cb[i], nullptr, nullptr, nxt);
        swap();
        mconv<4, false, true, false, false, false>
            <<<grid, 512, 0, stream>>>(cur, wfix + (3 + i) * FIXW, b_hr[i], nullptr, nullptr, nxt);
        swap();
    }
    mconv<4, false, true, false, false, false>
        <<<grid, 512, 0, stream>>>(cur, wfix + 6 * FIXW, b_hr[3], nullptr, nullptr, nxt);
    swap();
    mconv<4, false, true, false, false, false>
        <<<grid, 512, 0, stream>>>(cur, wfix + 7 * FIXW, b_hr[4], nullptr, nullptr, nxt);
    swap();
    mconv<1, false, true, false, false, true>
        <<<grid, 512, 0, stream>>>(cur, wlast, b_last, nullptr, nullptr, d_out);
}